// Round 14
// baseline (168.422 us; speedup 1.0000x reference)
//
#include <hip/hip_runtime.h>
#include <cstdint>
#include <cstddef>

#define N_PIX   16384
#define K_EMB   8192
#define DDIM    256

// ws layout (bytes)
// Af8: [mb=128][kk=4][r=128][64B]; Ef8 same + 16B-slot swizzle s^=(r>>1)&3
#define WS_A8       0           // 4194304
#define WS_E8       4194304     // 2097152
#define WS_KEYS     6291456     // keys [32 pools][16384] uint2   4194304
#define WS_ZSQ      23068672    // 16384*4
#define WS_ESQ      23134208    // 8192*4
#define WS_LOSS     23166976    // 8
#define WS_CNT      23166984    // 4

typedef float f32x16 __attribute__((ext_vector_type(16)));
typedef int   i32x4  __attribute__((ext_vector_type(4)));
typedef int   i32x8  __attribute__((ext_vector_type(8)));

__device__ __forceinline__ unsigned int f32_sortable(float f) {
    unsigned int u = __float_as_uint(f);
    return (u & 0x80000000u) ? ~u : (u | 0x80000000u);
}

// fp32 -> OCP e4m3fn RNE (fallback path; handles subnormals)
__device__ __forceinline__ unsigned char f2fp8(float x) {
    unsigned ub = __float_as_uint(x);
    unsigned sgn = (ub >> 24) & 0x80u;
    unsigned b = ub & 0x7FFFFFFFu;
    unsigned out;
    if (__uint_as_float(b) < 0.015625f) {
        out = (unsigned)(int)rintf(__uint_as_float(b) * 512.0f);
    } else {
        unsigned r = b + 0x7FFFFu + ((b >> 20) & 1u);
        int er = (int)(r >> 23) - 127;
        out = (unsigned)(((er + 7) << 3) | ((r >> 20) & 7u));
    }
    return (unsigned char)(out | sgn);
}

#if defined(__has_builtin)
#if __has_builtin(__builtin_amdgcn_cvt_pk_fp8_f32)
#define HAVE_CVT_FP8 1
#endif
#if __has_builtin(__builtin_amdgcn_fmed3f)
#define HAVE_FMED3 1
#endif
#endif

__device__ __forceinline__ unsigned pack4_fp8(float a, float b, float c, float d) {
#ifdef HAVE_CVT_FP8
    int pk = 0;
    pk = __builtin_amdgcn_cvt_pk_fp8_f32(a, b, pk, false);
    pk = __builtin_amdgcn_cvt_pk_fp8_f32(c, d, pk, true);
    return (unsigned)pk;
#else
    return (unsigned)f2fp8(a) | ((unsigned)f2fp8(b) << 8)
         | ((unsigned)f2fp8(c) << 16) | ((unsigned)f2fp8(d) << 24);
#endif
}

__device__ __forceinline__ void async16(const unsigned char* g, unsigned char* l) {
    __builtin_amdgcn_global_load_lds(
        (const __attribute__((address_space(1))) void*)g,
        (__attribute__((address_space(3))) void*)l, 16, 0, 0);
}

// np pairwise-sum of squares over 256 contiguous LDS floats (one thread)
__device__ __forceinline__ float np_pairwise_sq256(const float* row) {
    float r[16];
#pragma unroll
    for (int j = 0; j < 16; ++j) r[j] = 0.f;
#pragma unroll
    for (int c = 0; c < 256; ++c) {
        float x  = row[c];
        float sq = __fmul_rn(x, x);
        int slot = ((c >> 7) << 3) | (c & 7);
        r[slot] = __fadd_rn(r[slot], sq);
    }
    float h0 = __fadd_rn(
        __fadd_rn(__fadd_rn(r[0], r[1]), __fadd_rn(r[2], r[3])),
        __fadd_rn(__fadd_rn(r[4], r[5]), __fadd_rn(r[6], r[7])));
    float h1 = __fadd_rn(
        __fadd_rn(__fadd_rn(r[8], r[9]), __fadd_rn(r[10], r[11])),
        __fadd_rn(__fadd_rn(r[12], r[13]), __fadd_rn(r[14], r[15])));
    return __fadd_rn(h0, h1);
}

// ---------------------------------------------------------------- kernel 1
// R14: z-branch re-geometry for DRAM efficiency. 128 z-blocks own 128 px
// (one Af8 tile) x 256 c, processed in 8 c-chunks of 32: z reads become
// 512B segments (was 128B @4KB stride). zsq slot-chain order preserved
// EXACTLY (per-slot c ascending across chunks + identical 16-leaf tree).
// emb branch unchanged (256 blocks, contiguous reads).
__global__ __launch_bounds__(256) void prep_kernel(
        const float* __restrict__ z, const float* __restrict__ emb,
        unsigned char* __restrict__ Af8, unsigned char* __restrict__ Ef8,
        float* __restrict__ zsq, float* __restrict__ esq,
        double* __restrict__ lossAcc, unsigned* __restrict__ doneCnt) {
    union SH {
        struct { float tz[32][132]; float sacc[128][17]; } zp;  // 25.6 KB
        struct { float tile[32][257]; float sqs[32][17]; } ep;  // 35.1 KB
    };
    __shared__ SH sh;
    int blk = blockIdx.x;
    int t   = threadIdx.x;
    if (blk < 128) {
        int b = blk >> 3, mbl = blk & 7;
        const float* zb = z + (size_t)b * 262144 + mbl * 128;
        // init sacc
        for (int i = t; i < 128 * 17; i += 256)
            ((float*)sh.zp.sacc)[i] = 0.f;
#pragma unroll 1
        for (int ch = 0; ch < 8; ++ch) {
            int c0 = ch * 32;
            __syncthreads();   // tz free (prev consume done; also covers init)
#pragma unroll
            for (int s = 0; s < 4; ++s) {
                int u = t + 256 * s;
                int row = u >> 5, col4 = u & 31;
                float4 v = *(const float4*)&zb[(size_t)(c0 + row) * 1024
                                               + col4 * 4];
                *(float4*)&sh.zp.tz[row][col4 * 4] = v;
            }
            __syncthreads();
            // pack + write Af8: 2 threads per r, 16B each
            {
                int r = t >> 1, cb = (t & 1) * 16;
                uint4 val;
                val.x = pack4_fp8(sh.zp.tz[cb + 0][r],  sh.zp.tz[cb + 1][r],
                                  sh.zp.tz[cb + 2][r],  sh.zp.tz[cb + 3][r]);
                val.y = pack4_fp8(sh.zp.tz[cb + 4][r],  sh.zp.tz[cb + 5][r],
                                  sh.zp.tz[cb + 6][r],  sh.zp.tz[cb + 7][r]);
                val.z = pack4_fp8(sh.zp.tz[cb + 8][r],  sh.zp.tz[cb + 9][r],
                                  sh.zp.tz[cb + 10][r], sh.zp.tz[cb + 11][r]);
                val.w = pack4_fp8(sh.zp.tz[cb + 12][r], sh.zp.tz[cb + 13][r],
                                  sh.zp.tz[cb + 14][r], sh.zp.tz[cb + 15][r]);
                *(uint4*)(Af8 + (size_t)blk * 32768 + (c0 >> 6) * 8192
                          + r * 64 + (c0 & 32) + (t & 1) * 16) = val;
            }
            // sacc: 2 threads per r, 4 slots each, c ascending within slot
            {
                int r  = t >> 1;
                int sb = (c0 >= 128) ? 8 : 0;
#pragma unroll
                for (int q = 0; q < 4; ++q) {
                    int j0 = (t & 1) * 4 + q;
                    float v = sh.zp.sacc[r][sb + j0];
#pragma unroll
                    for (int m = 0; m < 4; ++m) {
                        float x = sh.zp.tz[j0 + 8 * m][r];
                        v = __fadd_rn(v, __fmul_rn(x, x));
                    }
                    sh.zp.sacc[r][sb + j0] = v;
                }
            }
        }
        __syncthreads();
        if (t < 128) {
            const float* r = sh.zp.sacc[t];
            float h0 = __fadd_rn(
                __fadd_rn(__fadd_rn(r[0], r[1]), __fadd_rn(r[2], r[3])),
                __fadd_rn(__fadd_rn(r[4], r[5]), __fadd_rn(r[6], r[7])));
            float h1 = __fadd_rn(
                __fadd_rn(__fadd_rn(r[8], r[9]), __fadd_rn(r[10], r[11])),
                __fadd_rn(__fadd_rn(r[12], r[13]), __fadd_rn(r[14], r[15])));
            zsq[(size_t)b * 1024 + mbl * 128 + t] = __fadd_rn(h0, h1);
        }
        if (blk == 0 && t == 0) { *lossAcc = 0.0; *doneCnt = 0u; }
    } else {
        int k0 = (blk - 128) * 32;
        const float4* eg = (const float4*)(emb + (size_t)k0 * DDIM);
#pragma unroll
        for (int i = 0; i < 8; ++i) {
            int idx = i * 256 + t;
            int row = idx >> 6, c4 = idx & 63;
            float4 v = eg[idx];
            *(float4*)&sh.ep.tile[row][c4 * 4] = v;
        }
        __syncthreads();
#pragma unroll
        for (int i = 0; i < 8; ++i) {
            int idx = i * 256 + t;
            int row = idx >> 6, c4 = idx & 63;
            const float* rp = &sh.ep.tile[row][c4 * 4];
            int kg = k0 + row;
            int nbb = kg >> 7, rr = kg & 127;
            int c  = c4 * 4;
            int kk = c >> 6, kl = c & 63;
            int s  = kl >> 4;
            int pos = kk * 8192 + rr * 64
                    + ((s ^ ((rr >> 1) & 3)) << 4) + (kl & 15);
            *(unsigned*)(Ef8 + (size_t)nbb * 32768 + pos) =
                pack4_fp8(rp[0] * 8192.0f, rp[1] * 8192.0f,
                          rp[2] * 8192.0f, rp[3] * 8192.0f);
        }
        {
            int row = t >> 3, s0 = t & 7;
            const float* rp = sh.ep.tile[row];
            float a0 = 0.f, a1 = 0.f;
#pragma unroll
            for (int i = 0; i < 16; ++i) {
                float x0 = rp[s0 + 8 * i];
                a0 = __fadd_rn(a0, __fmul_rn(x0, x0));
            }
#pragma unroll
            for (int i = 0; i < 16; ++i) {
                float x1 = rp[128 + s0 + 8 * i];
                a1 = __fadd_rn(a1, __fmul_rn(x1, x1));
            }
            sh.ep.sqs[row][s0]     = a0;
            sh.ep.sqs[row][s0 + 8] = a1;
        }
        __syncthreads();
        if (t < 32) {
            const float* r = sh.ep.sqs[t];
            float h0 = __fadd_rn(
                __fadd_rn(__fadd_rn(r[0], r[1]), __fadd_rn(r[2], r[3])),
                __fadd_rn(__fadd_rn(r[4], r[5]), __fadd_rn(r[6], r[7])));
            float h1 = __fadd_rn(
                __fadd_rn(__fadd_rn(r[8], r[9]), __fadd_rn(r[10], r[11])),
                __fadd_rn(__fadd_rn(r[12], r[13]), __fadd_rn(r[14], r[15])));
            esq[k0 + t] = __fadd_rn(h0, h1);
        }
    }
}

// winner float (idx in low 13 mantissa bits) -> integer key
__device__ __forceinline__ unsigned pack_key(float w) {
    float uf = __builtin_fmaf(w, -512.0f, 262144.0f);
    uf = fminf(uf, 524287.0f);
    unsigned u = (unsigned)uf;
    return (u << 13) | (__float_as_uint(w) & 0x1FFFu);
}

// ---------------------------------------------------------------- kernel 2
// unchanged from R13 (MX 32x32x64, reg-lean; verified 54.9 us)
__global__ __launch_bounds__(256) void mfma_score_kernel(
        const unsigned char* __restrict__ Af8,
        const unsigned char* __restrict__ Ef8,
        unsigned int* __restrict__ keys) {
    union __align__(16) SM {
        unsigned char Bs[2][32768];
        struct { uint2 ep[128][33]; } e;
    };
    __shared__ SM sm;

    const int g  = blockIdx.x;
    const int mb = blockIdx.y;
    const int t = threadIdx.x;
    const int w = t >> 6, lane = t & 63;
    const int l31 = lane & 31, h = lane >> 5;

    {
        const unsigned char* Eg = Ef8 + (size_t)(g * 4) * 32768 + t * 16;
#pragma unroll
        for (int ch = 0; ch < 8; ++ch)
            async16(Eg + ch * 4096, &sm.Bs[0][ch * 4096 + t * 16]);
    }

    i32x8 afr[4];
    {
        const unsigned char* Ab = Af8 + (size_t)mb * 32768;
        int r = w * 32 + l31;
#pragma unroll
        for (int kk = 0; kk < 4; ++kk) {
            const unsigned char* p = Ab + kk * 8192 + r * 64 + h * 32;
            i32x4 lo = *(const i32x4*)p;
            i32x4 hi = *(const i32x4*)(p + 16);
            afr[kk] = __builtin_shufflevector(lo, hi, 0, 1, 2, 3, 4, 5, 6, 7);
        }
    }

    const float NEGINF = __int_as_float(0xFF800000);
    float t2a[16], t2b[16];
#pragma unroll
    for (int q = 0; q < 16; ++q) { t2a[q] = NEGINF; t2b[q] = NEGINF; }

    __syncthreads();

#pragma unroll 1
    for (int j = 0; j < 4; ++j) {
        const int cur = j & 1, nxt = cur ^ 1;

        if (j < 3) {
            const unsigned char* Eg =
                Ef8 + (size_t)(g * 4 + j + 1) * 32768 + t * 16;
#pragma unroll
            for (int ch = 0; ch < 8; ++ch)
                async16(Eg + ch * 4096, &sm.Bs[nxt][ch * 4096 + t * 16]);
        }

        const int nb = g * 4 + j;
#pragma unroll
        for (int ct = 0; ct < 4; ++ct) {
            f32x16 acc;
#pragma unroll
            for (int q = 0; q < 16; ++q) acc[q] = 0.f;

            const int c  = ct * 32 + l31;
            const int m  = (c >> 1) & 3;
            const int s0 = h * 2;
            __builtin_amdgcn_s_setprio(1);
#pragma unroll
            for (int kk = 0; kk < 4; ++kk) {
                int base = kk * 8192 + c * 64;
                i32x4 lo = *(const i32x4*)
                    &sm.Bs[cur][base + ((s0 ^ m) << 4)];
                i32x4 hi = *(const i32x4*)
                    &sm.Bs[cur][base + (((s0 + 1) ^ m) << 4)];
                i32x8 bf = __builtin_shufflevector(lo, hi,
                                                   0, 1, 2, 3, 4, 5, 6, 7);
                acc = __builtin_amdgcn_mfma_scale_f32_32x32x64_f8f6f4(
                        afr[kk], bf, acc,
                        0, 0,
                        0, 0x7F7F7F7F,
                        0, 0x7F7F7F7F);
            }
            __builtin_amdgcn_s_setprio(0);

            const unsigned idxc = (unsigned)(nb * 128 + c);
#pragma unroll
            for (int q = 0; q < 16; ++q) {
                float v = acc[q];
                float wv = __uint_as_float(
                    (__float_as_uint(v) & 0xFFFFE000u) | idxc);
                float a0 = t2a[q], b0 = t2b[q];
#ifdef HAVE_FMED3
                float bn = __builtin_amdgcn_fmed3f(a0, wv, b0);
                t2a[q] = fmaxf(a0, wv);
                t2b[q] = bn;
#else
                float mn = fminf(a0, wv);
                t2a[q] = fmaxf(a0, wv);
                t2b[q] = fmaxf(b0, mn);
#endif
            }
        }
        __syncthreads();
    }

#pragma unroll
    for (int q = 0; q < 16; ++q) {
        int row = w * 32 + (q & 3) + 8 * (q >> 2) + 4 * h;
        sm.e.ep[row][l31] = make_uint2(pack_key(t2a[q]), pack_key(t2b[q]));
    }
    __syncthreads();

    {
        int row = t >> 1, half = t & 1, h0 = half * 16;
        uint2 mv = sm.e.ep[row][h0];
#pragma unroll
        for (int i = 1; i < 16; ++i) {
            uint2 av = sm.e.ep[row][h0 + i];
            unsigned n0 = min(mv.x, av.x);
            unsigned n1 = min(max(mv.x, av.x), min(mv.y, av.y));
            mv.x = n0; mv.y = n1;
        }
        ((uint2*)keys)[(size_t)(g * 2 + half) * N_PIX + (mb * 128 + row)] = mv;
    }
}

// ---------------------------------------------------------------- kernel 3
// R14: final_idx = R12 final truncated after Phase C (idx only).
__global__ __launch_bounds__(256) void final_kernel(
        const unsigned int* __restrict__ keys,
        const float* __restrict__ z, const float* __restrict__ emb,
        const float* __restrict__ zsq, const float* __restrict__ esq,
        float* __restrict__ idx_out) {
    __shared__ float ztile[32][257];
    __shared__ uint2 kt[32][33];
    __shared__ unsigned short scand[32][64];
    __shared__ unsigned long long ckey[2048];
    __shared__ int   soff[33];
    __shared__ int   scnt[32];
    __shared__ unsigned char pxmap[2048];
    __shared__ float szs[32];

    int blk = blockIdx.x;                // 0..511 = b*32 + hh2
    int b = blk >> 5, hh2 = blk & 31;
    int t = threadIdx.x;
    int p0 = b * 1024 + hh2 * 32;
    const float* zb = z + (size_t)b * 262144 + hh2 * 32;
    {
        int c0 = t >> 3, px4 = t & 7;
#pragma unroll
        for (int cc = 0; cc < 8; ++cc) {
            int c = cc * 32 + c0;
            float4 v = *(const float4*)&zb[(size_t)c * 1024 + px4 * 4];
            ztile[px4 * 4 + 0][c] = v.x;
            ztile[px4 * 4 + 1][c] = v.y;
            ztile[px4 * 4 + 2][c] = v.z;
            ztile[px4 * 4 + 3][c] = v.w;
        }
    }
    {
        const uint2* kg = (const uint2*)keys;
#pragma unroll
        for (int itr = 0; itr < 4; ++itr) {
            int idx = itr * 256 + t;
            int px = idx & 31, hf = idx >> 5;
            kt[px][hf] = kg[(size_t)hf * N_PIX + p0 + px];
        }
    }
    if (t < 32) szs[t] = zsq[p0 + t];
    __syncthreads();

    // ---- Phase A: threshold + compact candidate lists (4 waves x 8 px)
    {
        int wq = t >> 6, lane = t & 63;
#pragma unroll 1
        for (int i = 0; i < 8; ++i) {
            int px = wq * 8 + i;
            uint2 ka = (lane < 32) ? kt[px][lane] : make_uint2(~0u, ~0u);
            unsigned m = min(ka.x, ka.y);
#pragma unroll
            for (int off = 32; off >= 1; off >>= 1)
                m = min(m, (unsigned)__shfl_xor((int)m, off, 64));
            unsigned thr = (m >> 13) + 1600;   // margin 1600*2^-21 = 7.6e-4

            bool h0 = (lane < 32) && ((ka.x >> 13) <= thr);
            bool h1 = (lane < 32) && ((ka.y >> 13) <= thr);
            unsigned long long m0 = __ballot(h0);
            unsigned long long m1 = __ballot(h1);
            int c0 = __popcll(m0);
            unsigned long long below = (lane == 63) ? ~0ull >> 1
                                     : ((1ull << lane) - 1);
            if (h0) scand[px][__popcll(m0 & below)] =
                (unsigned short)(ka.x & 0x1FFFu);
            if (h1) scand[px][c0 + __popcll(m1 & below)] =
                (unsigned short)(ka.y & 0x1FFFu);
            if (lane == 0) scnt[px] = c0 + __popcll(m1);
        }
    }
    __syncthreads();

    if (t < 64) {
        int v = (t < 32) ? scnt[t] : 0;
#pragma unroll
        for (int o = 1; o < 32; o <<= 1) {
            int u = __shfl_up(v, o, 64);
            if (t >= o) v += u;
        }
        if (t < 32) soff[t + 1] = v;
        if (t == 0) soff[0] = 0;
    }
    __syncthreads();
    int total = soff[32];
    for (int f = t; f < total; f += 256) {
        int lo = 0, hi = 31;
        while (lo < hi) {
            int mid = (lo + hi + 1) >> 1;
            if (soff[mid] <= f) lo = mid; else hi = mid - 1;
        }
        pxmap[f] = (unsigned char)lo;
    }
    __syncthreads();

    // ---- Phase B: parallel rescore
    {
        int gid = t >> 4, l16 = t & 15;
        const float4* emb4 = (const float4*)emb;
#pragma unroll 1
        for (int f = gid; f < total; f += 16) {
            int px = pxmap[f];
            int k  = scand[px][f - soff[px]];
            double d = 0.0;
#pragma unroll
            for (int q = 0; q < 4; ++q) {
                float4 ev = emb4[(size_t)k * 64 + q * 16 + l16];
                const float* zp = &ztile[px][(q * 16 + l16) * 4];
                d += (double)zp[0] * ev.x + (double)zp[1] * ev.y
                   + (double)zp[2] * ev.z + (double)zp[3] * ev.w;
            }
#pragma unroll
            for (int o = 1; o < 16; o <<= 1) d += __shfl_xor(d, o, 64);
            if (l16 == 0) {
                float df = (float)d;
                float s  = __fsub_rn(__fadd_rn(szs[px], esq[k]),
                                     __fmul_rn(2.0f, df));
                ckey[f] = ((unsigned long long)f32_sortable(s) << 32)
                        | (unsigned)k;
            }
        }
    }
    __syncthreads();

    // ---- Phase C: per-pixel u64 min -> idx_out
    {
        int ci = t & 15;
#pragma unroll
        for (int pass = 0; pass < 2; ++pass) {
            int cpx = (t >> 4) + pass * 16;
            unsigned long long best = ~0ull;
            for (int f = soff[cpx] + ci; f < soff[cpx + 1]; f += 16) {
                unsigned long long v = ckey[f];
                best = v < best ? v : best;
            }
#pragma unroll
            for (int o = 1; o < 16; o <<= 1) {
                unsigned long long ov =
                    (unsigned long long)__shfl_xor((long long)best, o, 64);
                best = ov < best ? ov : best;
            }
            if (ci == 0)
                idx_out[p0 + cpx] = (float)(int)(unsigned)(best & 0xffffffffu);
        }
    }
}

// ---------------------------------------------------------------- kernel 4
// R14 new: contiguous out-writer + loss. 128 blocks x 128 px; per c-chunk
// of 32: gather emb rows into LDS-transposed etile, write out as 512B
// segments (was 128B), accumulate loss; double-atomic finalize.
__global__ __launch_bounds__(256) void write_kernel(
        const float* __restrict__ z, const float* __restrict__ emb,
        const float* __restrict__ idx_in, float* __restrict__ out,
        float* __restrict__ loss_out,
        double* __restrict__ lossAcc, unsigned* __restrict__ doneCnt) {
    __shared__ float etile[32][132];   // [c-rel][px], padded
    __shared__ int   kidx[128];
    __shared__ float wsum[4];
    int blk = blockIdx.x;              // 0..127 = b*8 + mbl
    int b = blk >> 3, mbl = blk & 7;
    int t = threadIdx.x;
    size_t pbase = (size_t)b * 1024 + mbl * 128;
    if (t < 128) kidx[t] = (int)idx_in[pbase + t];
    const float* zb = z + (size_t)b * 262144 + mbl * 128;
    float* ob = out + (size_t)b * 262144 + mbl * 128;
    float local = 0.f;
    __syncthreads();
#pragma unroll 1
    for (int ch = 0; ch < 8; ++ch) {
        int c0 = ch * 32;
        if (ch) __syncthreads();       // etile free
        {   // gather: 2 threads per px, 16 scalars each into transposed tile
            int px = t >> 1, part = t & 1;
            int k = kidx[px];
            const float4* er = (const float4*)(emb + (size_t)k * 256 + c0);
#pragma unroll
            for (int i = 0; i < 4; ++i) {
                float4 v = er[part * 4 + i];
                int cr = part * 16 + i * 4;
                etile[cr + 0][px] = v.x;
                etile[cr + 1][px] = v.y;
                etile[cr + 2][px] = v.z;
                etile[cr + 3][px] = v.w;
            }
        }
        __syncthreads();
        {   // out write (float4, 512B rows) + loss
            int row = t >> 3;          // c-rel 0..31
            int pxb = (t & 7) * 16;
#pragma unroll
            for (int s2 = 0; s2 < 4; ++s2) {
                int px = pxb + s2 * 4;
                float4 zv = *(const float4*)&zb[(size_t)(c0 + row) * 1024 + px];
                float4 ev = *(const float4*)&etile[row][px];
                *(float4*)&ob[(size_t)(c0 + row) * 1024 + px] = ev;
                float d0 = ev.x - zv.x, d1 = ev.y - zv.y;
                float d2 = ev.z - zv.z, d3 = ev.w - zv.w;
                local += d0 * d0 + d1 * d1 + d2 * d2 + d3 * d3;
            }
        }
    }
#pragma unroll
    for (int off = 32; off >= 1; off >>= 1)
        local += __shfl_down(local, off, 64);
    if ((t & 63) == 0) wsum[t >> 6] = local;
    __syncthreads();
    if (t == 0) {
        double s = (double)wsum[0] + (double)wsum[1]
                 + (double)wsum[2] + (double)wsum[3];
        atomicAdd(lossAcc, s);
        __threadfence();
        unsigned old = atomicAdd(doneCnt, 1u);
        if (old == 127u) {
            double tot = atomicAdd(lossAcc, 0.0);
            *loss_out = (float)(tot * (1.25 / 4194304.0));
        }
    }
}

// ----------------------------------------------------------------
extern "C" void kernel_launch(void* const* d_in, const int* in_sizes, int n_in,
                              void* d_out, int out_size, void* d_ws, size_t ws_size,
                              hipStream_t stream) {
    const float* z   = (const float*)d_in[0];
    const float* emb = (const float*)d_in[1];
    float* out = (float*)d_out;
    char* ws = (char*)d_ws;

    unsigned char* Af8 = (unsigned char*)(ws + WS_A8);
    unsigned char* Ef8 = (unsigned char*)(ws + WS_E8);
    unsigned int* keys = (unsigned int*)(ws + WS_KEYS);
    float* zsq      = (float*)(ws + WS_ZSQ);
    float* esq      = (float*)(ws + WS_ESQ);
    double* lossAcc = (double*)(ws + WS_LOSS);
    unsigned* doneCnt = (unsigned*)(ws + WS_CNT);

    prep_kernel<<<384, 256, 0, stream>>>(z, emb, Af8, Ef8, zsq, esq,
                                         lossAcc, doneCnt);
    mfma_score_kernel<<<dim3(16, 128), 256, 0, stream>>>(Af8, Ef8, keys);
    final_kernel<<<512, 256, 0, stream>>>(keys, z, emb, zsq, esq,
                                          out + 4194305);
    write_kernel<<<128, 256, 0, stream>>>(z, emb, out + 4194305, out,
                                          out + 4194304, lossAcc, doneCnt);
}

// Round 15
// 167.149 us; speedup vs baseline: 1.0076x; 1.0076x over previous
//
#include <hip/hip_runtime.h>
#include <cstdint>
#include <cstddef>

#define N_PIX   16384
#define K_EMB   8192
#define DDIM    256

// ws layout (bytes)
// Af8: [mb=128][kk=4][r=128][64B]; Ef8 same + 16B-slot swizzle s^=(r>>1)&3
#define WS_A8       0           // 4194304
#define WS_E8       4194304     // 2097152
#define WS_KEYS     6291456     // keys [32 pools][16384] uint2   4194304
#define WS_ZSQ      23068672    // 16384*4
#define WS_ESQ      23134208    // 8192*4
#define WS_LOSS     23166976    // 8
#define WS_CNT      23166984    // 4

typedef float f32x16 __attribute__((ext_vector_type(16)));
typedef int   i32x4  __attribute__((ext_vector_type(4)));
typedef int   i32x8  __attribute__((ext_vector_type(8)));

__device__ __forceinline__ unsigned int f32_sortable(float f) {
    unsigned int u = __float_as_uint(f);
    return (u & 0x80000000u) ? ~u : (u | 0x80000000u);
}

// fp32 -> OCP e4m3fn RNE (fallback path; handles subnormals)
__device__ __forceinline__ unsigned char f2fp8(float x) {
    unsigned ub = __float_as_uint(x);
    unsigned sgn = (ub >> 24) & 0x80u;
    unsigned b = ub & 0x7FFFFFFFu;
    unsigned out;
    if (__uint_as_float(b) < 0.015625f) {
        out = (unsigned)(int)rintf(__uint_as_float(b) * 512.0f);
    } else {
        unsigned r = b + 0x7FFFFu + ((b >> 20) & 1u);
        int er = (int)(r >> 23) - 127;
        out = (unsigned)(((er + 7) << 3) | ((r >> 20) & 7u));
    }
    return (unsigned char)(out | sgn);
}

#if defined(__has_builtin)
#if __has_builtin(__builtin_amdgcn_cvt_pk_fp8_f32)
#define HAVE_CVT_FP8 1
#endif
#if __has_builtin(__builtin_amdgcn_fmed3f)
#define HAVE_FMED3 1
#endif
#endif

__device__ __forceinline__ unsigned pack4_fp8(float a, float b, float c, float d) {
#ifdef HAVE_CVT_FP8
    int pk = 0;
    pk = __builtin_amdgcn_cvt_pk_fp8_f32(a, b, pk, false);
    pk = __builtin_amdgcn_cvt_pk_fp8_f32(c, d, pk, true);
    return (unsigned)pk;
#else
    return (unsigned)f2fp8(a) | ((unsigned)f2fp8(b) << 8)
         | ((unsigned)f2fp8(c) << 16) | ((unsigned)f2fp8(d) << 24);
#endif
}

__device__ __forceinline__ void async16(const unsigned char* g, unsigned char* l) {
    __builtin_amdgcn_global_load_lds(
        (const __attribute__((address_space(1))) void*)g,
        (__attribute__((address_space(3))) void*)l, 16, 0, 0);
}

// ---------------------------------------------------------------- kernel 1
// R15 = R13 prep verbatim (wave-parallel sq; R11 layouts)
__global__ __launch_bounds__(256) void prep_kernel(
        const float* __restrict__ z, const float* __restrict__ emb,
        unsigned char* __restrict__ Af8, unsigned char* __restrict__ Ef8,
        float* __restrict__ zsq, float* __restrict__ esq,
        double* __restrict__ lossAcc, unsigned* __restrict__ doneCnt) {
    __shared__ float tile[32][257];
    __shared__ float sqs[32][17];
    int blk = blockIdx.x;
    int t   = threadIdx.x;
    if (blk < 512) {
        int b   = blk >> 5;
        int hw0 = (blk & 31) * 32;
        const float* zb = z + (size_t)b * 262144 + hw0;
        int c0  = t >> 3;
        int px4 = t & 7;
#pragma unroll
        for (int cc = 0; cc < 8; ++cc) {
            int c = cc * 32 + c0;
            float4 v = *(const float4*)&zb[(size_t)c * 1024 + px4 * 4];
            tile[px4 * 4 + 0][c] = v.x;
            tile[px4 * 4 + 1][c] = v.y;
            tile[px4 * 4 + 2][c] = v.z;
            tile[px4 * 4 + 3][c] = v.w;
        }
        __syncthreads();
        int p0 = b * 1024 + hw0;
        int wv = t >> 6, lane = t & 63;
#pragma unroll
        for (int iter = 0; iter < 8; ++iter) {
            int pl = iter * 4 + wv;
            unsigned pk = pack4_fp8(tile[pl][lane * 4 + 0], tile[pl][lane * 4 + 1],
                                    tile[pl][lane * 4 + 2], tile[pl][lane * 4 + 3]);
            int p  = p0 + pl;
            int mbb = p >> 7, r = p & 127;
            int c = lane * 4;
            *(unsigned*)(Af8 + (size_t)mbb * 32768
                         + (c >> 6) * 8192 + r * 64 + (c & 63)) = pk;
        }
        {
            int row = t >> 3, s0 = t & 7;
            const float* rp = tile[row];
            float a0 = 0.f, a1 = 0.f;
#pragma unroll
            for (int i = 0; i < 16; ++i) {
                float x0 = rp[s0 + 8 * i];
                a0 = __fadd_rn(a0, __fmul_rn(x0, x0));
            }
#pragma unroll
            for (int i = 0; i < 16; ++i) {
                float x1 = rp[128 + s0 + 8 * i];
                a1 = __fadd_rn(a1, __fmul_rn(x1, x1));
            }
            sqs[row][s0]     = a0;
            sqs[row][s0 + 8] = a1;
        }
        __syncthreads();
        if (t < 32) {
            const float* r = sqs[t];
            float h0 = __fadd_rn(
                __fadd_rn(__fadd_rn(r[0], r[1]), __fadd_rn(r[2], r[3])),
                __fadd_rn(__fadd_rn(r[4], r[5]), __fadd_rn(r[6], r[7])));
            float h1 = __fadd_rn(
                __fadd_rn(__fadd_rn(r[8], r[9]), __fadd_rn(r[10], r[11])),
                __fadd_rn(__fadd_rn(r[12], r[13]), __fadd_rn(r[14], r[15])));
            zsq[p0 + t] = __fadd_rn(h0, h1);
        }
        if (blk == 0 && t == 0) { *lossAcc = 0.0; *doneCnt = 0u; }
    } else {
        int k0 = (blk - 512) * 32;
        const float4* eg = (const float4*)(emb + (size_t)k0 * DDIM);
#pragma unroll
        for (int i = 0; i < 8; ++i) {
            int idx = i * 256 + t;
            int row = idx >> 6, c4 = idx & 63;
            float4 v = eg[idx];
            *(float4*)&tile[row][c4 * 4] = v;
        }
        __syncthreads();
#pragma unroll
        for (int i = 0; i < 8; ++i) {
            int idx = i * 256 + t;
            int row = idx >> 6, c4 = idx & 63;
            const float* rp = &tile[row][c4 * 4];
            int kg = k0 + row;
            int nbb = kg >> 7, rr = kg & 127;
            int c  = c4 * 4;
            int kk = c >> 6, kl = c & 63;
            int s  = kl >> 4;
            int pos = kk * 8192 + rr * 64
                    + ((s ^ ((rr >> 1) & 3)) << 4) + (kl & 15);
            *(unsigned*)(Ef8 + (size_t)nbb * 32768 + pos) =
                pack4_fp8(rp[0] * 8192.0f, rp[1] * 8192.0f,
                          rp[2] * 8192.0f, rp[3] * 8192.0f);
        }
        {
            int row = t >> 3, s0 = t & 7;
            const float* rp = tile[row];
            float a0 = 0.f, a1 = 0.f;
#pragma unroll
            for (int i = 0; i < 16; ++i) {
                float x0 = rp[s0 + 8 * i];
                a0 = __fadd_rn(a0, __fmul_rn(x0, x0));
            }
#pragma unroll
            for (int i = 0; i < 16; ++i) {
                float x1 = rp[128 + s0 + 8 * i];
                a1 = __fadd_rn(a1, __fmul_rn(x1, x1));
            }
            sqs[row][s0]     = a0;
            sqs[row][s0 + 8] = a1;
        }
        __syncthreads();
        if (t < 32) {
            const float* r = sqs[t];
            float h0 = __fadd_rn(
                __fadd_rn(__fadd_rn(r[0], r[1]), __fadd_rn(r[2], r[3])),
                __fadd_rn(__fadd_rn(r[4], r[5]), __fadd_rn(r[6], r[7])));
            float h1 = __fadd_rn(
                __fadd_rn(__fadd_rn(r[8], r[9]), __fadd_rn(r[10], r[11])),
                __fadd_rn(__fadd_rn(r[12], r[13]), __fadd_rn(r[14], r[15])));
            esq[k0 + t] = __fadd_rn(h0, h1);
        }
    }
}

// winner float (idx in low 13 mantissa bits) -> integer key
__device__ __forceinline__ unsigned pack_key(float w) {
    float uf = __builtin_fmaf(w, -512.0f, 262144.0f);
    uf = fminf(uf, 524287.0f);
    unsigned u = (unsigned)uf;
    return (u << 13) | (__float_as_uint(w) & 0x1FFFu);
}

// ---------------------------------------------------------------- kernel 2
// R15: R13 score + g0 offset, launched as TWO dim3(8,128) dispatches so
// each half (~28 us) drops below prep/final in the top-5 — diagnostic
// visibility round. Keys pools disjoint per half; A-frags re-read (L2).
__global__ __launch_bounds__(256) void mfma_score_kernel(
        const unsigned char* __restrict__ Af8,
        const unsigned char* __restrict__ Ef8,
        unsigned int* __restrict__ keys, int g0) {
    union __align__(16) SM {
        unsigned char Bs[2][32768];
        struct { uint2 ep[128][33]; } e;
    };
    __shared__ SM sm;

    const int g  = blockIdx.x + g0;
    const int mb = blockIdx.y;
    const int t = threadIdx.x;
    const int w = t >> 6, lane = t & 63;
    const int l31 = lane & 31, h = lane >> 5;

    {
        const unsigned char* Eg = Ef8 + (size_t)(g * 4) * 32768 + t * 16;
#pragma unroll
        for (int ch = 0; ch < 8; ++ch)
            async16(Eg + ch * 4096, &sm.Bs[0][ch * 4096 + t * 16]);
    }

    i32x8 afr[4];
    {
        const unsigned char* Ab = Af8 + (size_t)mb * 32768;
        int r = w * 32 + l31;
#pragma unroll
        for (int kk = 0; kk < 4; ++kk) {
            const unsigned char* p = Ab + kk * 8192 + r * 64 + h * 32;
            i32x4 lo = *(const i32x4*)p;
            i32x4 hi = *(const i32x4*)(p + 16);
            afr[kk] = __builtin_shufflevector(lo, hi, 0, 1, 2, 3, 4, 5, 6, 7);
        }
    }

    const float NEGINF = __int_as_float(0xFF800000);
    float t2a[16], t2b[16];
#pragma unroll
    for (int q = 0; q < 16; ++q) { t2a[q] = NEGINF; t2b[q] = NEGINF; }

    __syncthreads();

#pragma unroll 1
    for (int j = 0; j < 4; ++j) {
        const int cur = j & 1, nxt = cur ^ 1;

        if (j < 3) {
            const unsigned char* Eg =
                Ef8 + (size_t)(g * 4 + j + 1) * 32768 + t * 16;
#pragma unroll
            for (int ch = 0; ch < 8; ++ch)
                async16(Eg + ch * 4096, &sm.Bs[nxt][ch * 4096 + t * 16]);
        }

        const int nb = g * 4 + j;
#pragma unroll
        for (int ct = 0; ct < 4; ++ct) {
            f32x16 acc;
#pragma unroll
            for (int q = 0; q < 16; ++q) acc[q] = 0.f;

            const int c  = ct * 32 + l31;
            const int m  = (c >> 1) & 3;
            const int s0 = h * 2;
            __builtin_amdgcn_s_setprio(1);
#pragma unroll
            for (int kk = 0; kk < 4; ++kk) {
                int base = kk * 8192 + c * 64;
                i32x4 lo = *(const i32x4*)
                    &sm.Bs[cur][base + ((s0 ^ m) << 4)];
                i32x4 hi = *(const i32x4*)
                    &sm.Bs[cur][base + (((s0 + 1) ^ m) << 4)];
                i32x8 bf = __builtin_shufflevector(lo, hi,
                                                   0, 1, 2, 3, 4, 5, 6, 7);
                acc = __builtin_amdgcn_mfma_scale_f32_32x32x64_f8f6f4(
                        afr[kk], bf, acc,
                        0, 0,
                        0, 0x7F7F7F7F,
                        0, 0x7F7F7F7F);
            }
            __builtin_amdgcn_s_setprio(0);

            const unsigned idxc = (unsigned)(nb * 128 + c);
#pragma unroll
            for (int q = 0; q < 16; ++q) {
                float v = acc[q];
                float wv = __uint_as_float(
                    (__float_as_uint(v) & 0xFFFFE000u) | idxc);
                float a0 = t2a[q], b0 = t2b[q];
#ifdef HAVE_FMED3
                float bn = __builtin_amdgcn_fmed3f(a0, wv, b0);
                t2a[q] = fmaxf(a0, wv);
                t2b[q] = bn;
#else
                float mn = fminf(a0, wv);
                t2a[q] = fmaxf(a0, wv);
                t2b[q] = fmaxf(b0, mn);
#endif
            }
        }
        __syncthreads();
    }

#pragma unroll
    for (int q = 0; q < 16; ++q) {
        int row = w * 32 + (q & 3) + 8 * (q >> 2) + 4 * h;
        sm.e.ep[row][l31] = make_uint2(pack_key(t2a[q]), pack_key(t2b[q]));
    }
    __syncthreads();

    {
        int row = t >> 1, half = t & 1, h0 = half * 16;
        uint2 mv = sm.e.ep[row][h0];
#pragma unroll
        for (int i = 1; i < 16; ++i) {
            uint2 av = sm.e.ep[row][h0 + i];
            unsigned n0 = min(mv.x, av.x);
            unsigned n1 = min(max(mv.x, av.x), min(mv.y, av.y));
            mv.x = n0; mv.y = n1;
        }
        ((uint2*)keys)[(size_t)(g * 2 + half) * N_PIX + (mb * 128 + row)] = mv;
    }
}

// ---------------------------------------------------------------- kernel 3
// R15 = R13 final verbatim (32-px blocks, idx + gather + loss)
__global__ __launch_bounds__(256) void final_kernel(
        const unsigned int* __restrict__ keys,
        const float* __restrict__ z, const float* __restrict__ emb,
        const float* __restrict__ zsq, const float* __restrict__ esq,
        float* __restrict__ out, float* __restrict__ idx_out,
        float* __restrict__ loss_out,
        double* __restrict__ lossAcc, unsigned* __restrict__ doneCnt) {
    __shared__ float ztile[32][257];
    __shared__ uint2 kt[32][33];
    __shared__ unsigned short scand[32][64];
    __shared__ unsigned long long ckey[2048];
    __shared__ int   soff[33];
    __shared__ int   scnt[32];
    __shared__ unsigned char pxmap[2048];
    __shared__ float szs[32];
    __shared__ int   sidx[32];

    int blk = blockIdx.x;                // 0..511 = b*32 + hh2
    int b = blk >> 5, hh2 = blk & 31;
    int t = threadIdx.x;
    int p0 = b * 1024 + hh2 * 32;
    const float* zb = z + (size_t)b * 262144 + hh2 * 32;
    {
        int c0 = t >> 3, px4 = t & 7;
#pragma unroll
        for (int cc = 0; cc < 8; ++cc) {
            int c = cc * 32 + c0;
            float4 v = *(const float4*)&zb[(size_t)c * 1024 + px4 * 4];
            ztile[px4 * 4 + 0][c] = v.x;
            ztile[px4 * 4 + 1][c] = v.y;
            ztile[px4 * 4 + 2][c] = v.z;
            ztile[px4 * 4 + 3][c] = v.w;
        }
    }
    {
        const uint2* kg = (const uint2*)keys;
#pragma unroll
        for (int itr = 0; itr < 4; ++itr) {
            int idx = itr * 256 + t;
            int px = idx & 31, hf = idx >> 5;
            kt[px][hf] = kg[(size_t)hf * N_PIX + p0 + px];
        }
    }
    if (t < 32) szs[t] = zsq[p0 + t];
    __syncthreads();

    // ---- Phase A: threshold + compact candidate lists (4 waves x 8 px)
    {
        int wq = t >> 6, lane = t & 63;
#pragma unroll 1
        for (int i = 0; i < 8; ++i) {
            int px = wq * 8 + i;
            uint2 ka = (lane < 32) ? kt[px][lane] : make_uint2(~0u, ~0u);
            unsigned m = min(ka.x, ka.y);
#pragma unroll
            for (int off = 32; off >= 1; off >>= 1)
                m = min(m, (unsigned)__shfl_xor((int)m, off, 64));
            unsigned thr = (m >> 13) + 1600;   // margin 1600*2^-21 = 7.6e-4

            bool h0 = (lane < 32) && ((ka.x >> 13) <= thr);
            bool h1 = (lane < 32) && ((ka.y >> 13) <= thr);
            unsigned long long m0 = __ballot(h0);
            unsigned long long m1 = __ballot(h1);
            int c0 = __popcll(m0);
            unsigned long long below = (lane == 63) ? ~0ull >> 1
                                     : ((1ull << lane) - 1);
            if (h0) scand[px][__popcll(m0 & below)] =
                (unsigned short)(ka.x & 0x1FFFu);
            if (h1) scand[px][c0 + __popcll(m1 & below)] =
                (unsigned short)(ka.y & 0x1FFFu);
            if (lane == 0) scnt[px] = c0 + __popcll(m1);
        }
    }
    __syncthreads();

    // ---- scan 32 counts -> soff (wave 0), then pxmap
    if (t < 64) {
        int v = (t < 32) ? scnt[t] : 0;
#pragma unroll
        for (int o = 1; o < 32; o <<= 1) {
            int u = __shfl_up(v, o, 64);
            if (t >= o) v += u;
        }
        if (t < 32) soff[t + 1] = v;
        if (t == 0) soff[0] = 0;
    }
    __syncthreads();
    int total = soff[32];
    for (int f = t; f < total; f += 256) {
        int lo = 0, hi = 31;
        while (lo < hi) {
            int mid = (lo + hi + 1) >> 1;
            if (soff[mid] <= f) lo = mid; else hi = mid - 1;
        }
        pxmap[f] = (unsigned char)lo;
    }
    __syncthreads();

    // ---- Phase B: parallel rescore, one candidate per 16-lane group
    {
        int gid = t >> 4, l16 = t & 15;
        const float4* emb4 = (const float4*)emb;
#pragma unroll 1
        for (int f = gid; f < total; f += 16) {
            int px = pxmap[f];
            int k  = scand[px][f - soff[px]];
            double d = 0.0;
#pragma unroll
            for (int q = 0; q < 4; ++q) {
                float4 ev = emb4[(size_t)k * 64 + q * 16 + l16];
                const float* zp = &ztile[px][(q * 16 + l16) * 4];
                d += (double)zp[0] * ev.x + (double)zp[1] * ev.y
                   + (double)zp[2] * ev.z + (double)zp[3] * ev.w;
            }
#pragma unroll
            for (int o = 1; o < 16; o <<= 1) d += __shfl_xor(d, o, 64);
            if (l16 == 0) {
                float df = (float)d;
                float s  = __fsub_rn(__fadd_rn(szs[px], esq[k]),
                                     __fmul_rn(2.0f, df));
                ckey[f] = ((unsigned long long)f32_sortable(s) << 32)
                        | (unsigned)k;
            }
        }
    }
    __syncthreads();

    // ---- Phase C: per-pixel u64 min (16 threads each, 2 passes)
    {
        int ci = t & 15;
#pragma unroll
        for (int pass = 0; pass < 2; ++pass) {
            int cpx = (t >> 4) + pass * 16;
            unsigned long long best = ~0ull;
            for (int f = soff[cpx] + ci; f < soff[cpx + 1]; f += 16) {
                unsigned long long v = ckey[f];
                best = v < best ? v : best;
            }
#pragma unroll
            for (int o = 1; o < 16; o <<= 1) {
                unsigned long long ov =
                    (unsigned long long)__shfl_xor((long long)best, o, 64);
                best = ov < best ? ov : best;
            }
            if (ci == 0) {
                int k = (int)(unsigned)(best & 0xffffffffu);
                sidx[cpx] = k;
                idx_out[p0 + cpx] = (float)k;
            }
        }
    }
    __syncthreads();

    // ---- gather + loss (128B-segment stores)
    int px2 = t & 31, cy = t >> 5;
    int kk = sidx[px2];
    const float* er = emb + (size_t)kk * DDIM;
    float* ob = out + (size_t)b * 262144 + hh2 * 32;
    float local = 0.f;
#pragma unroll 4
    for (int it = 0; it < 32; ++it) {
        int c = it * 8 + cy;
        float q = er[c];
        float d = q - ztile[px2][c];
        ob[(size_t)c * 1024 + px2] = q;
        local += d * d;
    }
#pragma unroll
    for (int off = 32; off >= 1; off >>= 1) local += __shfl_down(local, off, 64);
    __shared__ float wsum[4];
    if ((t & 63) == 0) wsum[t >> 6] = local;
    __syncthreads();
    if (t == 0) {
        double s = (double)wsum[0] + (double)wsum[1]
                 + (double)wsum[2] + (double)wsum[3];
        atomicAdd(lossAcc, s);
        __threadfence();
        unsigned old = atomicAdd(doneCnt, 1u);
        if (old == 511u) {
            double tot = atomicAdd(lossAcc, 0.0);
            *loss_out = (float)(tot * (1.25 / 4194304.0));
        }
    }
}

// ----------------------------------------------------------------
extern "C" void kernel_launch(void* const* d_in, const int* in_sizes, int n_in,
                              void* d_out, int out_size, void* d_ws, size_t ws_size,
                              hipStream_t stream) {
    const float* z   = (const float*)d_in[0];
    const float* emb = (const float*)d_in[1];
    float* out = (float*)d_out;
    char* ws = (char*)d_ws;

    unsigned char* Af8 = (unsigned char*)(ws + WS_A8);
    unsigned char* Ef8 = (unsigned char*)(ws + WS_E8);
    unsigned int* keys = (unsigned int*)(ws + WS_KEYS);
    float* zsq      = (float*)(ws + WS_ZSQ);
    float* esq      = (float*)(ws + WS_ESQ);
    double* lossAcc = (double*)(ws + WS_LOSS);
    unsigned* doneCnt = (unsigned*)(ws + WS_CNT);

    prep_kernel<<<768, 256, 0, stream>>>(z, emb, Af8, Ef8, zsq, esq,
                                         lossAcc, doneCnt);
    mfma_score_kernel<<<dim3(8, 128), 256, 0, stream>>>(Af8, Ef8, keys, 0);
    mfma_score_kernel<<<dim3(8, 128), 256, 0, stream>>>(Af8, Ef8, keys, 8);
    final_kernel<<<512, 256, 0, stream>>>(keys, z, emb, zsq, esq,
                                          out, out + 4194305, out + 4194304,
                                          lossAcc, doneCnt);
}